// Round 1
// 445.911 us; speedup vs baseline: 1.0652x; 1.0652x over previous
//
#include <hip/hip_runtime.h>
#include <hip/hip_bf16.h>
#include <cmath>

#define N_SPH 7
#define N_RAD 6
#define NC (N_SPH * N_RAD)   // 42
#define INV_CUTOFF 0.2f

typedef float f2 __attribute__((ext_vector_type(2)));
typedef float f4 __attribute__((ext_vector_type(4)));

struct BesselConsts {
    float freq[NC];     // z_{l,j}, l-major
    float norm[NC];     // sqrt(2)/|j_{l+1}(z_{l,j})|
    float ycoef[N_SPH]; // sqrt((2l+1)/4pi)
};

// ---------------- host-side precompute (graph-capture time only) ----------
static double h_sph_jn(double t, int l) {
    double j0 = sin(t) / t;
    if (l == 0) return j0;
    double j1 = sin(t) / (t * t) - cos(t) / t;
    for (int i = 2; i <= l; i++) {
        double j2 = (2.0 * i - 1.0) / t * j1 - j0;
        j0 = j1; j1 = j2;
    }
    return j1;
}

static void compute_consts(BesselConsts* bc) {
    const int n = N_SPH, k = N_RAD, nz = N_RAD + N_SPH - 1;  // 12
    const double PI = 3.14159265358979323846;
    double zeros[N_SPH][12];
    for (int i = 0; i < nz; i++) zeros[0][i] = (i + 1) * PI;
    for (int l = 1; l < n; l++) {
        for (int i = 0; i < nz - l; i++) {
            double a = zeros[l - 1][i], b = zeros[l - 1][i + 1];
            double fa = h_sph_jn(a, l);
            for (int it = 0; it < 80; it++) {
                double m = 0.5 * (a + b);
                double fm = h_sph_jn(m, l);
                if (fa * fm <= 0.0) { b = m; } else { a = m; fa = fm; }
            }
            zeros[l][i] = 0.5 * (a + b);
        }
    }
    for (int l = 0; l < n; l++)
        for (int j = 0; j < k; j++) {
            bc->freq[l * k + j] = (float)zeros[l][j];
            bc->norm[l * k + j] =
                (float)(sqrt(2.0) / fabs(h_sph_jn(zeros[l][j], l + 1)));
        }
    for (int l = 0; l < n; l++)
        bc->ycoef[l] = (float)sqrt((2.0 * l + 1.0) / (4.0 * PI));
}

// ---------------- kernel A: per-edge radial table [E,42] fp32 -------------
// Fully unrolled (l,j): all BesselConsts indices compile-time -> kernarg
// s_loads, no scratch. f32 sincos seed + f64 Newton-refined 1/t + f64 upward
// recurrence (seed error amplified ~1e4x at l=6, t~1 -> keeps absmax ~0.25).
// Stage is PACKED (stride 42): 4-way LDS write conflict during compute
// (negligible vs ~4600-cycle compute phase) buys a contiguous float4
// copy-out. Table stores are NORMAL (we WANT the table resident in L2/L3
// for out_kernel's gather).
__global__ __launch_bounds__(256) void rbf_kernel(
    const float* __restrict__ dist, float* __restrict__ rbf, int E_,
    BesselConsts bc) {
    __shared__ __align__(16) float stage[256 * NC];
    const int tix = threadIdx.x;
    const int e0 = blockIdx.x * 256;
    const int e = e0 + tix;
    const bool valid = e < E_;
    float x = valid ? dist[e] * INV_CUTOFF : 0.5f;
    float xp = x * x * x * x * x;  // x^5
    // p=5 envelope: 1/x + x^5*(-21 + x*(35 - 15x))
    float env = 1.0f / x + xp * (-21.0f + x * (35.0f - 15.0f * x));

#pragma unroll
    for (int l = 0; l < N_SPH; ++l) {
#pragma unroll
        for (int j = 0; j < N_RAD; ++j) {
            const int c = l * N_RAD + j;
            float tt = x * bc.freq[c];
            float s, co;
            sincosf(tt, &s, &co);
            float rf = 1.0f / tt;                 // f32 IEEE div (cheap seq)
            double r = (double)rf;
            r = r * (2.0 - (double)tt * r);       // Newton: ~1e-15 rel
            double jv;
            double j0 = (double)s * r;
            if (l == 0) {
                jv = j0;
            } else {
                double j1 = ((double)s * r - (double)co) * r;
#pragma unroll
                for (int i = 2; i <= l; ++i) {
                    double j2 = (2.0 * i - 1.0) * r * j1 - j0;
                    j0 = j1; j1 = j2;
                }
                jv = j1;
            }
            stage[tix * NC + c] = env * bc.norm[c] * (float)jv;
        }
    }
    __syncthreads();
    // coalesced float4 copy-out: 256*42/4 = 2688 f4 per full block
    const int rows = min(256, E_ - e0);
    const int nelem = rows * NC;
    const int n4 = nelem >> 2;
    const size_t base = (size_t)e0 * NC;
#pragma unroll
    for (int it = 0; it < 11; ++it) {
        int i = it * 256 + tix;
        if (i < n4) {
            f4 v = *reinterpret_cast<const f4*>(&stage[4 * i]);
            *reinterpret_cast<f4*>(rbf + base + 4 * (size_t)i) = v;
        }
    }
    // scalar tail (only if rows odd; never for E=500000 but keep general)
    for (int i = n4 * 4 + tix; i < nelem; i += 256) rbf[base + i] = stage[i];
}

// ---------------- kernel B: per-row angular + gather ----------------------
// Phase 1: each thread computes cos + all 7 ycoef*P_l once into LDS.
// Phase 2: PAIR sweep (21 f2 per row). Invariants (NC=42 even, row stride
// even): an (even,odd) element pair never crosses a row, is 8B-aligned in
// both rbf and out, and shares the same l (c even => c/6 == (c+1)/6).
// Each pair: 2 LDS reads + 1 dwordx2 gather + 2 fmul + 1 NT dwordx2 store.
// Stores are NON-TEMPORAL so the 336 MB out-stream doesn't evict the 84 MB
// rbf table from L2/L3 (the table has 4x reuse: T/E = 4).
__global__ __launch_bounds__(256) void out_kernel(
    const float* __restrict__ angle, const int* __restrict__ idx,
    const float* __restrict__ rbf, float* __restrict__ out, int T_,
    BesselConsts bc) {
    __shared__ float yP[256 * 8];  // stride 8
    __shared__ int sidx[256];
    const int tix = threadIdx.x;
    const int t0 = blockIdx.x * 256;
    const int t = t0 + tix;

    float cth = 0.0f;
    int id = 0;
    if (t < T_) {
        cth = cosf(angle[t]);
        id = idx[t];
    }
    float P[N_SPH];
    P[0] = 1.0f;
    P[1] = cth;
#pragma unroll
    for (int l = 2; l < N_SPH; ++l)
        P[l] = ((2 * l - 1) * cth * P[l - 1] - (l - 1) * P[l - 2]) *
               (1.0f / (float)l);
#pragma unroll
    for (int l = 0; l < N_SPH; ++l) yP[tix * 8 + l] = bc.ycoef[l] * P[l];
    sidx[tix] = id;
    __syncthreads();

    const int rows = min(256, T_ - t0);
    const int npair = rows * (NC / 2);          // rows*21
    const size_t base = (size_t)t0 * NC;
#pragma unroll
    for (int it = 0; it < NC / 2; ++it) {       // 21 iterations
        int pi = it * 256 + tix;
        if (pi < npair) {
            unsigned row = (unsigned)pi / 21u;              // magic mul
            unsigned c = 2u * ((unsigned)pi - row * 21u);   // even, < 42
            unsigned l = c / 6u;                            // magic mul
            const f2 rv =
                *reinterpret_cast<const f2*>(rbf + (size_t)sidx[row] * NC + c);
            float y = yP[row * 8 + l];
            f2 o;
            o.x = y * rv.x;
            o.y = y * rv.y;
            __builtin_nontemporal_store(
                o, reinterpret_cast<f2*>(out + base + 2 * (size_t)pi));
        }
    }
}

// ---------------- fallback: fused, no workspace (correctness path) --------
__global__ __launch_bounds__(256) void fused_kernel(
    const float* __restrict__ dist, const float* __restrict__ angle,
    const int* __restrict__ idx, float* __restrict__ out, int ntot,
    BesselConsts bc) {
    int tid = blockIdx.x * 256 + threadIdx.x;
    if (tid >= ntot) return;
    int t = tid / NC;
    int c = tid - t * NC;
    int l = c / N_RAD;
    int e = idx[t];
    float x = dist[e] * INV_CUTOFF;
    float tt = x * bc.freq[c];
    float s, co;
    sincosf(tt, &s, &co);
    double r = 1.0 / (double)tt;
    double j0 = (double)s * r, jv;
    if (l == 0) jv = j0;
    else {
        double j1 = ((double)s * r - (double)co) * r;
        for (int i = 2; i <= l; ++i) {
            double j2 = (2.0 * i - 1.0) * r * j1 - j0;
            j0 = j1; j1 = j2;
        }
        jv = j1;
    }
    float xp = x * x * x * x * x;
    float env = 1.0f / x + xp * (-21.0f + x * (35.0f - 15.0f * x));
    float p0 = 1.0f, p1 = cosf(angle[t]), pl = (l == 0) ? 1.0f : p1;
    for (int i = 2; i <= l; ++i) {
        float p2 = ((2 * i - 1) * p1 * cosf(angle[t]) - (i - 1) * p0) / i;
        p0 = p1; p1 = p2; pl = p2;
    }
    out[tid] = bc.ycoef[l] * pl * env * bc.norm[c] * (float)jv;
}

extern "C" void kernel_launch(void* const* d_in, const int* in_sizes, int n_in,
                              void* d_out, int out_size, void* d_ws,
                              size_t ws_size, hipStream_t stream) {
    const float* dist = (const float*)d_in[0];
    const float* angle = (const float*)d_in[1];
    const int* idx = (const int*)d_in[2];
    float* out = (float*)d_out;

    int E_ = in_sizes[0];
    int T_ = in_sizes[1];
    int na = E_ * NC;
    int nb = T_ * NC;

    BesselConsts bc;
    compute_consts(&bc);

    if (ws_size >= (size_t)na * sizeof(float)) {
        float* rbf = (float*)d_ws;
        rbf_kernel<<<(E_ + 255) / 256, 256, 0, stream>>>(dist, rbf, E_, bc);
        out_kernel<<<(T_ + 255) / 256, 256, 0, stream>>>(angle, idx, rbf, out,
                                                         T_, bc);
    } else {
        fused_kernel<<<(nb + 255) / 256, 256, 0, stream>>>(dist, angle, idx,
                                                           out, nb, bc);
    }
}

// Round 3
// 418.218 us; speedup vs baseline: 1.1357x; 1.0662x over previous
//
#include <hip/hip_runtime.h>
#include <hip/hip_bf16.h>
#include <cmath>

#define N_SPH 7
#define N_RAD 6
#define NC (N_SPH * N_RAD)   // 42
#define INV_CUTOFF 0.2f

typedef float f2 __attribute__((ext_vector_type(2)));
typedef float f4 __attribute__((ext_vector_type(4)));

struct BesselConsts {
    float freq[NC];     // z_{l,j}, l-major
    float norm[NC];     // sqrt(2)/|j_{l+1}(z_{l,j})|
    float ycoef[N_SPH]; // sqrt((2l+1)/4pi)
};

// ---------------- host-side precompute (graph-capture time only) ----------
static double h_sph_jn(double t, int l) {
    double j0 = sin(t) / t;
    if (l == 0) return j0;
    double j1 = sin(t) / (t * t) - cos(t) / t;
    for (int i = 2; i <= l; i++) {
        double j2 = (2.0 * i - 1.0) / t * j1 - j0;
        j0 = j1; j1 = j2;
    }
    return j1;
}

static void compute_consts(BesselConsts* bc) {
    const int n = N_SPH, k = N_RAD, nz = N_RAD + N_SPH - 1;  // 12
    const double PI = 3.14159265358979323846;
    double zeros[N_SPH][12];
    for (int i = 0; i < nz; i++) zeros[0][i] = (i + 1) * PI;
    for (int l = 1; l < n; l++) {
        for (int i = 0; i < nz - l; i++) {
            double a = zeros[l - 1][i], b = zeros[l - 1][i + 1];
            double fa = h_sph_jn(a, l);
            for (int it = 0; it < 80; it++) {
                double m = 0.5 * (a + b);
                double fm = h_sph_jn(m, l);
                if (fa * fm <= 0.0) { b = m; } else { a = m; fa = fm; }
            }
            zeros[l][i] = 0.5 * (a + b);
        }
    }
    for (int l = 0; l < n; l++)
        for (int j = 0; j < k; j++) {
            bc->freq[l * k + j] = (float)zeros[l][j];
            bc->norm[l * k + j] =
                (float)(sqrt(2.0) / fabs(h_sph_jn(zeros[l][j], l + 1)));
        }
    for (int l = 0; l < n; l++)
        bc->ycoef[l] = (float)sqrt((2.0 * l + 1.0) / (4.0 * PI));
}

// ---------------- fused row kernel: one thread per triplet row ------------
// Kills the 84 MB rbf table entirely: recomputing the 42 Bessel values per
// row costs ~1.5k VALU issues (T/E=4 redundancy, ~50 us chip-wide) but
// removes the table write (84 MB) + the random 168 B-row gather (~600 MB of
// cache-line traffic) + one kernel launch. The only random access left is
// dist[idx[t]] -- a 2 MB array, resident in every per-XCD L2.
//
// Numerics identical to the previous passing version: f32 sincos seed,
// f64 Newton-refined 1/t, f64 upward recurrence; multiply order
// yP * (env * norm * jv) preserved -> absmax unchanged.
//
// Per-row results staged packed in LDS (2-way write conflict = free), then
// NT float4 copy-out (write-only stream: bypass L2/L3, keep dist resident).
__global__ __launch_bounds__(256) void fused_row_kernel(
    const float* __restrict__ dist, const float* __restrict__ angle,
    const int* __restrict__ idx, float* __restrict__ out, int T_,
    BesselConsts bc) {
    __shared__ __align__(16) float stage[256 * NC];  // 43 KB -> 3 blocks/CU
    const int tix = threadIdx.x;
    const int t0 = blockIdx.x * 256;
    const int t = t0 + tix;
    const bool valid = t < T_;

    float x = 0.5f, cth = 0.0f;
    if (valid) {
        x = dist[idx[t]] * INV_CUTOFF;  // L2-resident random gather
        cth = cosf(angle[t]);
    }
    // p=5 envelope: 1/x + x^5*(-21 + x*(35 - 15x))
    float xp = x * x * x * x * x;
    float env = 1.0f / x + xp * (-21.0f + x * (35.0f - 15.0f * x));
    // Legendre P_l(cos th), then fold ycoef -> yP[l]
    float P[N_SPH];
    P[0] = 1.0f;
    P[1] = cth;
#pragma unroll
    for (int l = 2; l < N_SPH; ++l)
        P[l] = ((2 * l - 1) * cth * P[l - 1] - (l - 1) * P[l - 2]) *
               (1.0f / (float)l);
    float yP[N_SPH];
#pragma unroll
    for (int l = 0; l < N_SPH; ++l) yP[l] = bc.ycoef[l] * P[l];

#pragma unroll
    for (int l = 0; l < N_SPH; ++l) {
#pragma unroll
        for (int j = 0; j < N_RAD; ++j) {
            const int c = l * N_RAD + j;
            float tt = x * bc.freq[c];
            float s, co;
            sincosf(tt, &s, &co);
            float rf = 1.0f / tt;                 // f32 IEEE div seed
            double r = (double)rf;
            r = r * (2.0 - (double)tt * r);       // Newton: ~1e-15 rel
            double jv;
            double j0 = (double)s * r;
            if (l == 0) {
                jv = j0;
            } else {
                double j1 = ((double)s * r - (double)co) * r;
#pragma unroll
                for (int i = 2; i <= l; ++i) {
                    double j2 = (2.0 * i - 1.0) * r * j1 - j0;
                    j0 = j1; j1 = j2;
                }
                jv = j1;
            }
            // same multiply order as previous passing kernels:
            // rbf = env*norm*jv ; out = yP * rbf
            stage[tix * NC + c] = yP[l] * (env * bc.norm[c] * (float)jv);
        }
    }
    __syncthreads();

    // coalesced NT float4 copy-out: 256*42/4 = 2688 f4 per full block
    const int rows = min(256, T_ - t0);
    const int nelem = rows * NC;
    const int n4 = nelem >> 2;
    const size_t base = (size_t)t0 * NC;
#pragma unroll
    for (int it = 0; it < 11; ++it) {
        int i = it * 256 + tix;
        if (i < n4) {
            f4 v = *reinterpret_cast<const f4*>(&stage[4 * i]);
            __builtin_nontemporal_store(
                v, reinterpret_cast<f4*>(out + base + 4 * (size_t)i));
        }
    }
    for (int i = n4 * 4 + tix; i < nelem; i += 256)
        __builtin_nontemporal_store(stage[i], out + base + i);
}

extern "C" void kernel_launch(void* const* d_in, const int* in_sizes, int n_in,
                              void* d_out, int out_size, void* d_ws,
                              size_t ws_size, hipStream_t stream) {
    const float* dist = (const float*)d_in[0];
    const float* angle = (const float*)d_in[1];
    const int* idx = (const int*)d_in[2];
    float* out = (float*)d_out;

    int E_ = in_sizes[0];
    int T_ = in_sizes[1];
    (void)E_; (void)d_ws; (void)ws_size;

    BesselConsts bc;
    compute_consts(&bc);

    fused_row_kernel<<<(T_ + 255) / 256, 256, 0, stream>>>(dist, angle, idx,
                                                           out, T_, bc);
}

// Round 5
// 374.234 us; speedup vs baseline: 1.2692x; 1.1175x over previous
//
#include <hip/hip_runtime.h>
#include <hip/hip_bf16.h>
#include <cmath>

#define N_SPH 7
#define N_RAD 6
#define NC (N_SPH * N_RAD)   // 42
#define INV_CUTOFF 0.2f

typedef float f2 __attribute__((ext_vector_type(2)));
typedef float f4 __attribute__((ext_vector_type(4)));

// Compile-time m_c = round(z_c / (pi/2)), l-major. Integer table is robust:
// even if a borderline entry were off by one, host computes delta = z - m*pi/2
// consistently (identity sin(m*theta+u) holds for ANY m); polys below are
// padded to |u|<=1.6 to cover that case. Nominal |delta| <= 0.79.
static constexpr int M_TAB[NC] = {
    2,  4,  6,  8,  10, 12,   // l=0 (z = (j+1)*pi exactly -> delta = 0)
    3,  5,  7,  9,  11, 13,   // l=1
    4,  6,  8,  10, 12, 14,   // l=2
    4,  7,  9,  11, 13, 15,   // l=3
    5,  7,  10, 12, 14, 16,   // l=4
    6,  8,  10, 13, 15, 17,   // l=5
    7,  9,  11, 13, 15, 18};  // l=6

struct BesselConsts {
    float freq[NC];      // z_{l,j}, l-major
    float norm[NC];      // sqrt(2)/|j_{l+1}(z_{l,j})|
    float deltaf[NC];    // z - m*pi/2 (f32, for l<=3 path)
    float ycoef[N_SPH];  // sqrt((2l+1)/4pi)
    double deltad[NC];   // z - m*pi/2 (f64, for l>=4 path)
};

// ---------------- host-side precompute (graph-capture time only) ----------
static double h_sph_jn(double t, int l) {
    double j0 = sin(t) / t;
    if (l == 0) return j0;
    double j1 = sin(t) / (t * t) - cos(t) / t;
    for (int i = 2; i <= l; i++) {
        double j2 = (2.0 * i - 1.0) / t * j1 - j0;
        j0 = j1; j1 = j2;
    }
    return j1;
}

static void compute_consts(BesselConsts* bc) {
    const int n = N_SPH, k = N_RAD, nz = N_RAD + N_SPH - 1;  // 12
    const double PI = 3.14159265358979323846;
    const double PI_2 = 1.57079632679489661923;
    double zeros[N_SPH][12];
    for (int i = 0; i < nz; i++) zeros[0][i] = (i + 1) * PI;
    for (int l = 1; l < n; l++) {
        for (int i = 0; i < nz - l; i++) {
            double a = zeros[l - 1][i], b = zeros[l - 1][i + 1];
            double fa = h_sph_jn(a, l);
            for (int it = 0; it < 80; it++) {
                double m = 0.5 * (a + b);
                double fm = h_sph_jn(m, l);
                if (fa * fm <= 0.0) { b = m; } else { a = m; fa = fm; }
            }
            zeros[l][i] = 0.5 * (a + b);
        }
    }
    for (int l = 0; l < n; l++)
        for (int j = 0; j < k; j++) {
            const int c = l * k + j;
            bc->freq[c] = (float)zeros[l][j];
            bc->norm[c] =
                (float)(sqrt(2.0) / fabs(h_sph_jn(zeros[l][j], l + 1)));
            double dd = zeros[l][j] - (double)M_TAB[c] * PI_2;
            bc->deltad[c] = dd;
            bc->deltaf[c] = (float)dd;
        }
    for (int l = 0; l < n; l++)
        bc->ycoef[l] = (float)sqrt((2.0 * l + 1.0) / (4.0 * PI));
}

// ---------------- per-element device helpers ------------------------------
// l<=3: amplification of seed error by upward recurrence is <= ~60; full-f32
// path (seed poly, rcp+Newton, recurrence) keeps output error <= ~5e-3.
template <int L, int C_>
__device__ __forceinline__ void elem32(float x, float env, float Sf, float Cf,
                                       const float* yP, float* strow,
                                       const BesselConsts& bc) {
    float tt = x * bc.freq[C_];
    float u = x * bc.deltaf[C_];
    float v = u * u;
    // sin/cos small-angle polys, accurate to ~f32 ulp over |u|<=0.79
    // (still ~1e-7 abs at |u|<=1.6 boundary-misround case)
    float su = u * fmaf(v, fmaf(v, fmaf(v, fmaf(v, fmaf(v, -2.5052108e-8f,
                    2.7557319e-6f), -1.9841270e-4f), 8.3333333e-3f),
                    -1.6666667e-1f), 1.0f);
    float cu = fmaf(v, fmaf(v, fmaf(v, fmaf(v, fmaf(v, fmaf(v, 2.0876757e-9f,
                    -2.7557319e-7f), 2.4801587e-5f), -1.3888889e-3f),
                    4.1666667e-2f), -0.5f), 1.0f);
    float s = fmaf(Sf, cu, Cf * su);    // sin(m*th + u)
    float co = fmaf(Cf, cu, -(Sf * su)); // cos(m*th + u)
    float r = __builtin_amdgcn_rcpf(tt);
    r = r * fmaf(-tt, r, 2.0f);          // Newton -> ~0.5 ulp
    float jv;
    float j0 = s * r;
    if constexpr (L == 0) {
        jv = j0;
    } else {
        float j1 = fmaf(s, r, -co) * r;
#pragma unroll
        for (int i = 2; i <= L; ++i) {
            float j2 = fmaf((2.0f * i - 1.0f) * r, j1, -j0);
            j0 = j1; j1 = j2;
        }
        jv = j1;
    }
    strow[C_] = yP[L] * (env * bc.norm[C_] * jv);
}

// l>=4: seed sin/cos AND recurrence in f64 (amplification up to ~1e4 at
// small tt) -- seed is now f64-accurate, better than the old f32 sincosf.
template <int L, int C_>
__device__ __forceinline__ void elem64(float x, double xd, float env,
                                       double Sd, double Cd, const float* yP,
                                       float* strow, const BesselConsts& bc) {
    float tt = x * bc.freq[C_];
    double u = xd * bc.deltad[C_];
    double v = u * u;
    double su = u * fma(v, fma(v, fma(v, fma(v, fma(v, -1.0 / 39916800.0,
                     1.0 / 362880.0), -1.0 / 5040.0), 1.0 / 120.0),
                     -1.0 / 6.0), 1.0);
    double cu = fma(v, fma(v, fma(v, fma(v, fma(v, fma(v, 1.0 / 479001600.0,
                     -1.0 / 3628800.0), 1.0 / 40320.0), -1.0 / 720.0),
                     1.0 / 24.0), -0.5), 1.0);
    double s = fma(Sd, cu, Cd * su);
    double co = fma(Cd, cu, -(Sd * su));
    double td = (double)tt;
    float rf = __builtin_amdgcn_rcpf(tt);
    double r = (double)rf;
    r = r * fma(-td, r, 2.0);            // Newton in f64: ~1e-14 rel
    double j0 = s * r;
    double j1 = fma(s, r, -co) * r;      // L>=4 always here
#pragma unroll
    for (int i = 2; i <= L; ++i) {
        double j2 = fma((2.0 * i - 1.0) * r, j1, -j0);
        j0 = j1; j1 = j2;
    }
    strow[C_] = yP[L] * (env * bc.norm[C_] * (float)j1);
}

// ---------------- fused row kernel: one thread per triplet row ------------
// R3 showed this kernel is VALU-bound (~208 us, 1.6 TB/s eff. vs 53 us store
// roofline). Dominant cost was 42x OCML sincosf + f64. Replaced by ONE f64
// Taylor sin/cos of th = x*pi/2 (single interval, no range reduction), a
// 17-step f64 angle-addition chain visiting m=2..18, and per-element
// small-angle polys + 2-FMA combine, iterating elements in m-order with
// compile-time indices (no runtime-indexed arrays -> no scratch).
__global__ __launch_bounds__(256) void fused_row_kernel(
    const float* __restrict__ dist, const float* __restrict__ angle,
    const int* __restrict__ idx, float* __restrict__ out, int T_,
    BesselConsts bc) {
    __shared__ __align__(16) float stage[256 * NC];  // 43 KB -> 3 blocks/CU
    const int tix = threadIdx.x;
    const int t0 = blockIdx.x * 256;
    const int t = t0 + tix;
    const bool valid = t < T_;

    float x = 0.5f, cth = 0.0f;
    if (valid) {
        x = dist[idx[t]] * INV_CUTOFF;  // L2-resident random gather (2 MB)
        cth = cosf(angle[t]);
    }
    // p=5 envelope: 1/x + x^5*(-21 + x*(35 - 15x))
    float xp = x * x * x * x * x;
    float env = 1.0f / x + xp * (-21.0f + x * (35.0f - 15.0f * x));
    // Legendre P_l(cos th) -> yP[l] (compile-time indexed -> registers)
    float P[N_SPH];
    P[0] = 1.0f;
    P[1] = cth;
#pragma unroll
    for (int l = 2; l < N_SPH; ++l)
        P[l] = ((2 * l - 1) * cth * P[l - 1] - (l - 1) * P[l - 2]) *
               (1.0f / (float)l);
    float yP[N_SPH];
#pragma unroll
    for (int l = 0; l < N_SPH; ++l) yP[l] = bc.ycoef[l] * P[l];

    // f64 sin/cos of th = x*pi/2 over [0, pi/2]: single-interval Taylor,
    // error ~4e-11 -- no range reduction needed.
    double xd = (double)x;
    double th = xd * 1.57079632679489661923;
    double w = th * th;
    double s1 = th * fma(w, fma(w, fma(w, fma(w, fma(w, fma(w,
                     1.0 / 6227020800.0, -1.0 / 39916800.0), 1.0 / 362880.0),
                     -1.0 / 5040.0), 1.0 / 120.0), -1.0 / 6.0), 1.0);
    double c1 = fma(w, fma(w, fma(w, fma(w, fma(w, fma(w, fma(w,
                     -1.0 / 87178291200.0, 1.0 / 479001600.0),
                     -1.0 / 3628800.0), 1.0 / 40320.0), -1.0 / 720.0),
                     1.0 / 24.0), -0.5), 1.0);
    double S = s1, C = c1;  // (sin,cos) of m*th, currently m=1

    float* strow = &stage[tix * NC];

#define STEP() do { double Sn = fma(S, c1, C * s1); \
                    C = fma(C, c1, -(S * s1)); S = Sn; } while (0)
#define E32(L_, C_) do { float Sf = (float)S, Cf = (float)C; \
                         elem32<L_, C_>(x, env, Sf, Cf, yP, strow, bc); } while (0)
#define E64(L_, C_) elem64<L_, C_>(x, xd, env, S, C, yP, strow, bc)

    STEP();  E32(0, 0);                                   // m=2
    STEP();  E32(1, 6);                                   // m=3
    STEP();  E32(0, 1);  E32(2, 12); E32(3, 18);          // m=4
    STEP();  E32(1, 7);  E64(4, 24);                      // m=5
    STEP();  E32(0, 2);  E32(2, 13); E64(5, 30);          // m=6
    STEP();  E32(1, 8);  E32(3, 19); E64(4, 25); E64(6, 36); // m=7
    STEP();  E32(0, 3);  E32(2, 14); E64(5, 31);          // m=8
    STEP();  E32(1, 9);  E32(3, 20); E64(6, 37);          // m=9
    STEP();  E32(0, 4);  E32(2, 15); E64(4, 26); E64(5, 32); // m=10
    STEP();  E32(1, 10); E32(3, 21); E64(6, 38);          // m=11
    STEP();  E32(0, 5);  E32(2, 16); E64(4, 27);          // m=12
    STEP();  E32(1, 11); E32(3, 22); E64(5, 33); E64(6, 39); // m=13
    STEP();  E32(2, 17); E64(4, 28);                      // m=14
    STEP();  E32(3, 23); E64(5, 34); E64(6, 40);          // m=15
    STEP();  E64(4, 29);                                  // m=16
    STEP();  E64(5, 35);                                  // m=17
    STEP();  E64(6, 41);                                  // m=18
#undef STEP
#undef E32
#undef E64

    __syncthreads();

    // coalesced NT float4 copy-out: 256*42/4 = 2688 f4 per full block
    const int rows = min(256, T_ - t0);
    const int nelem = rows * NC;
    const int n4 = nelem >> 2;
    const size_t base = (size_t)t0 * NC;
#pragma unroll
    for (int it = 0; it < 11; ++it) {
        int i = it * 256 + tix;
        if (i < n4) {
            f4 v = *reinterpret_cast<const f4*>(&stage[4 * i]);
            __builtin_nontemporal_store(
                v, reinterpret_cast<f4*>(out + base + 4 * (size_t)i));
        }
    }
    for (int i = n4 * 4 + tix; i < nelem; i += 256)
        __builtin_nontemporal_store(stage[i], out + base + i);
}

extern "C" void kernel_launch(void* const* d_in, const int* in_sizes, int n_in,
                              void* d_out, int out_size, void* d_ws,
                              size_t ws_size, hipStream_t stream) {
    const float* dist = (const float*)d_in[0];
    const float* angle = (const float*)d_in[1];
    const int* idx = (const int*)d_in[2];
    float* out = (float*)d_out;

    int E_ = in_sizes[0];
    int T_ = in_sizes[1];
    (void)E_; (void)d_ws; (void)ws_size;

    BesselConsts bc;
    compute_consts(&bc);

    fused_row_kernel<<<(T_ + 255) / 256, 256, 0, stream>>>(dist, angle, idx,
                                                           out, T_, bc);
}